// Round 1
// baseline (259.876 us; speedup 1.0000x reference)
//
#include <hip/hip_runtime.h>

typedef unsigned int uint_t;
typedef unsigned short u16;
typedef __attribute__((ext_vector_type(4))) float f32x4;
typedef __attribute__((ext_vector_type(8))) __bf16 bf16x8;

#define S_TOT 20000
#define S_LD  20032   // padded V^T row stride
#define B_TOT 1024
#define NHEAD 4
#define NSPLIT 16
#define NCHUNK 313    // ceil(20000/64)

__device__ __forceinline__ u16 f2bf(float x) {
  uint_t u = __builtin_bit_cast(uint_t, x);
  u += 0x7FFFu + ((u >> 16) & 1u);
  return (u16)(u >> 16);
}

__device__ __forceinline__ bf16x8 ld_frag(const u16* p) {
  return __builtin_bit_cast(bf16x8, *(const uint4*)p);
}

// ---------------- weight conversion f32 -> bf16 ----------------
__global__ void convert_w(const float* __restrict__ ipw, const float* __restrict__ opw,
                          u16* __restrict__ wqkv, u16* __restrict__ wout) {
  int i = blockIdx.x * 256 + threadIdx.x;           // 0..262143
  if (i < 196608) wqkv[i] = f2bf(ipw[i]);
  else            wout[i - 196608] = f2bf(opw[i - 196608]);
}

// zero the padded tail columns of V^T (s in [20000,20032))
__global__ void zero_vt_pad(u16* __restrict__ vt) {
  int i = blockIdx.x * 256 + threadIdx.x;           // 8192 = 256 rows * 32
  int d = i >> 5, j = i & 31;
  vt[(size_t)d * S_LD + S_TOT + j] = 0;
}

// ---------------- column mean of embed (deterministic 2-stage) ----------------
__global__ void colmean_part(const float* __restrict__ emb, float* __restrict__ cmp) {
  int t = threadIdx.x, p = blockIdx.x;              // 80 blocks x 250 rows
  float s = 0.f;
  for (int r = p * 250; r < (p + 1) * 250; r++) s += emb[(size_t)r * 256 + t];
  cmp[p * 256 + t] = s;
}

__global__ void vmean_k(const float* __restrict__ cmp, const float* __restrict__ ipw,
                        const float* __restrict__ ipb, float* __restrict__ vm) {
  __shared__ float sm[256];
  int t = threadIdx.x;
  float s = 0.f;
  for (int p = 0; p < 80; p++) s += cmp[p * 256 + t];
  sm[t] = s * (1.0f / 20000.0f);
  __syncthreads();
  float acc = ipb[512 + t];
  const float* wv = ipw + (size_t)(512 + t) * 256;
  for (int c = 0; c < 256; c++) acc += sm[c] * wv[c];
  vm[t] = acc;
}

// ---------------- generic B^T GEMM: C[M x N] = A_f32[M x 256] @ W_bf16[N x 256]^T + bias ----
// MODE 0: out bf16 row-major [M][256]        (q projection)
// MODE 1: n<256 -> K bf16 [M][256]; n>=256 -> V^T bf16 [(n-256)][S_LD] (kv projection)
// MODE 2: out f32 row-major [M][256]         (output projection)
template<int MODE>
__launch_bounds__(256)
__global__ void gemm_bt(const float* __restrict__ A, const u16* __restrict__ W,
                        const float* __restrict__ bias, int M,
                        u16* __restrict__ ob, u16* __restrict__ kb,
                        u16* __restrict__ vtb, float* __restrict__ of) {
  __shared__ __align__(16) u16 sA[64][40];
  __shared__ __align__(16) u16 sW[64][40];
  const int t = threadIdx.x;
  const int w = t >> 6, lane = t & 63, lr = lane & 15, lg = lane >> 4;
  const int m0 = blockIdx.x * 64, n0 = blockIdx.y * 64;
  const int r = t >> 2, kc = (t & 3) * 8;
  f32x4 acc[4] = {};
  int ga = m0 + r; if (ga > M - 1) ga = M - 1;
  const float* ap = A + (size_t)ga * 256;
  const u16*   wp = W + (size_t)(n0 + r) * 256;
  for (int k0 = 0; k0 < 256; k0 += 32) {
    float4 a0 = *(const float4*)(ap + k0 + kc);
    float4 a1 = *(const float4*)(ap + k0 + kc + 4);
    uint4  wv = *(const uint4*)(wp + k0 + kc);
    uint4 pk;
    pk.x = f2bf(a0.x) | ((uint_t)f2bf(a0.y) << 16);
    pk.y = f2bf(a0.z) | ((uint_t)f2bf(a0.w) << 16);
    pk.z = f2bf(a1.x) | ((uint_t)f2bf(a1.y) << 16);
    pk.w = f2bf(a1.z) | ((uint_t)f2bf(a1.w) << 16);
    *(uint4*)&sA[r][kc] = pk;
    *(uint4*)&sW[r][kc] = wv;
    __syncthreads();
    bf16x8 af = ld_frag(&sA[16 * w + lr][lg * 8]);
#pragma unroll
    for (int nf = 0; nf < 4; nf++) {
      bf16x8 bfr = ld_frag(&sW[16 * nf + lr][lg * 8]);
      acc[nf] = __builtin_amdgcn_mfma_f32_16x16x32_bf16(af, bfr, acc[nf], 0, 0, 0);
    }
    __syncthreads();
  }
  const int rbase = m0 + 16 * w + lg * 4;
#pragma unroll
  for (int nf = 0; nf < 4; nf++) {
    const int n = n0 + nf * 16 + lr;
    const float bi = bias[n];
    if (MODE == 1) {
      if (n >= 256) {
        const int vr = n - 256;
        u16 b[4];
#pragma unroll
        for (int g = 0; g < 4; g++) b[g] = f2bf(acc[nf][g] + bi);
        if (rbase + 3 < M) {
          uint2 p2; p2.x = b[0] | ((uint_t)b[1] << 16); p2.y = b[2] | ((uint_t)b[3] << 16);
          *(uint2*)&vtb[(size_t)vr * S_LD + rbase] = p2;
        } else {
#pragma unroll
          for (int g = 0; g < 4; g++) if (rbase + g < M) vtb[(size_t)vr * S_LD + rbase + g] = b[g];
        }
      } else {
#pragma unroll
        for (int g = 0; g < 4; g++) if (rbase + g < M) kb[(size_t)(rbase + g) * 256 + n] = f2bf(acc[nf][g] + bi);
      }
    } else if (MODE == 0) {
#pragma unroll
      for (int g = 0; g < 4; g++) if (rbase + g < M) ob[(size_t)(rbase + g) * 256 + n] = f2bf(acc[nf][g] + bi);
    } else {
#pragma unroll
      for (int g = 0; g < 4; g++) if (rbase + g < M) of[(size_t)(rbase + g) * 256 + n] = acc[nf][g] + bi;
    }
  }
}

// ---------------- flash attention with split-S partials ----------------
// grid: (NSPLIT, B/64, H). Per WG: Q-tile 64 rows, 4 waves each own 16 q-rows.
__launch_bounds__(256)
__global__ void attn_k(const u16* __restrict__ qb, const u16* __restrict__ kb,
                       const u16* __restrict__ vt, const int* __restrict__ act,
                       float* __restrict__ pc, float* __restrict__ pml) {
  __shared__ __align__(16) u16 sQ[64][72];
  __shared__ __align__(16) u16 sK[64][72];
  __shared__ __align__(16) u16 sV[64][72];   // rows = d-local, cols = s-local (V^T tile)
  __shared__ __align__(16) u16 sP[4][16][72];
  __shared__ __align__(16) unsigned char sM[64][68];
  const int t = threadIdx.x;
  const int w = t >> 6, lane = t & 63, lr = lane & 15, lg = lane >> 4;
  const int si = blockIdx.x, bt = blockIdx.y, h = blockIdx.z;
  const int b0 = bt * 64;
  const int r = t >> 2, cc = (t & 3) * 16;

  { // stage Q tile once: rows b0..b0+63, cols = head slice
    const u16* src = qb + (size_t)(b0 + r) * 256 + h * 64 + cc;
    *(uint4*)&sQ[r][cc]     = *(const uint4*)src;
    *(uint4*)&sQ[r][cc + 8] = *(const uint4*)(src + 8);
  }
  f32x4 ctx[4] = {};
  float m[4] = {-3e38f, -3e38f, -3e38f, -3e38f};
  float l[4] = {0.f, 0.f, 0.f, 0.f};
  __syncthreads();

  for (int ci = si; ci < NCHUNK; ci += NSPLIT) {
    const int s0 = ci * 64;
    { // stage K (row-major), V^T, mask
      int sr = s0 + r; if (sr > S_TOT - 1) sr = S_TOT - 1;
      const u16* kp = kb + (size_t)sr * 256 + h * 64 + cc;
      *(uint4*)&sK[r][cc]     = *(const uint4*)kp;
      *(uint4*)&sK[r][cc + 8] = *(const uint4*)(kp + 8);
      const u16* vp = vt + (size_t)(h * 64 + r) * S_LD + s0 + cc;
      *(uint4*)&sV[r][cc]     = *(const uint4*)vp;
      *(uint4*)&sV[r][cc + 8] = *(const uint4*)(vp + 8);
      const int* apm = act + (size_t)(b0 + r) * S_TOT + s0 + cc;
#pragma unroll
      for (int q4 = 0; q4 < 4; q4++) {
        int sbase = s0 + cc + q4 * 4;
        uint_t pk = 0;
        if (sbase + 3 < S_TOT) {
          int4 av = *(const int4*)(apm + q4 * 4);
          pk = (av.x > 0 ? 1u : 0u) | (av.y > 0 ? 0x100u : 0u) |
               (av.z > 0 ? 0x10000u : 0u) | (av.w > 0 ? 0x1000000u : 0u);
        } else {
          for (int j = 0; j < 4; j++)
            if (sbase + j < S_TOT) pk |= (apm[q4 * 4 + j] > 0 ? 1u : 0u) << (8 * j);
        }
        *(uint_t*)&sM[r][cc + q4 * 4] = pk;
      }
    }
    __syncthreads();

    // ---- QK^T : S-strip 16x64 per wave ----
    f32x4 sc[4] = {};
#pragma unroll
    for (int kf = 0; kf < 2; kf++) {
      bf16x8 aq = ld_frag(&sQ[16 * w + lr][kf * 32 + lg * 8]);
#pragma unroll
      for (int nf = 0; nf < 4; nf++) {
        bf16x8 bk = ld_frag(&sK[nf * 16 + lr][kf * 32 + lg * 8]);
        sc[nf] = __builtin_amdgcn_mfma_f32_16x16x32_bf16(aq, bk, sc[nf], 0, 0, 0);
      }
    }
    // ---- mask + scale; C layout: row=(lg*4+reg) [q], col=lr [s] ----
#pragma unroll
    for (int nf = 0; nf < 4; nf++)
#pragma unroll
      for (int reg = 0; reg < 4; reg++) {
        unsigned char mk = sM[16 * w + lg * 4 + reg][nf * 16 + lr];
        float v = sc[nf][reg] * 0.125f;
        sc[nf][reg] = mk ? v : -1e9f;
      }
    // ---- online softmax ----
    float mc[4];
#pragma unroll
    for (int reg = 0; reg < 4; reg++)
      mc[reg] = fmaxf(fmaxf(sc[0][reg], sc[1][reg]), fmaxf(sc[2][reg], sc[3][reg]));
#pragma unroll
    for (int off = 1; off <= 8; off <<= 1)
#pragma unroll
      for (int reg = 0; reg < 4; reg++)
        mc[reg] = fmaxf(mc[reg], __shfl_xor(mc[reg], off));
    float al[4];
#pragma unroll
    for (int reg = 0; reg < 4; reg++) {
      float mn = fmaxf(m[reg], mc[reg]);
      al[reg] = __expf(m[reg] - mn);
      m[reg] = mn;
    }
    float ls[4] = {0.f, 0.f, 0.f, 0.f};
#pragma unroll
    for (int nf = 0; nf < 4; nf++)
#pragma unroll
      for (int reg = 0; reg < 4; reg++) {
        float p = __expf(sc[nf][reg] - m[reg]);
        sc[nf][reg] = p;
        ls[reg] += p;
      }
#pragma unroll
    for (int off = 1; off <= 8; off <<= 1)
#pragma unroll
      for (int reg = 0; reg < 4; reg++)
        ls[reg] += __shfl_xor(ls[reg], off);
#pragma unroll
    for (int reg = 0; reg < 4; reg++) l[reg] = l[reg] * al[reg] + ls[reg];
#pragma unroll
    for (int nf = 0; nf < 4; nf++)
#pragma unroll
      for (int reg = 0; reg < 4; reg++) ctx[nf][reg] *= al[reg];
    // ---- P -> LDS (wave-private) ----
#pragma unroll
    for (int nf = 0; nf < 4; nf++)
#pragma unroll
      for (int reg = 0; reg < 4; reg++)
        sP[w][lg * 4 + reg][nf * 16 + lr] = f2bf(sc[nf][reg]);
    // ---- PV ----
#pragma unroll
    for (int kf = 0; kf < 2; kf++) {
      bf16x8 ap = ld_frag(&sP[w][lr][kf * 32 + lg * 8]);
#pragma unroll
      for (int nf = 0; nf < 4; nf++) {
        bf16x8 bv = ld_frag(&sV[nf * 16 + lr][kf * 32 + lg * 8]);
        ctx[nf] = __builtin_amdgcn_mfma_f32_16x16x32_bf16(ap, bv, ctx[nf], 0, 0, 0);
      }
    }
    __syncthreads();
  }
  // ---- write partials ----
#pragma unroll
  for (int nf = 0; nf < 4; nf++)
#pragma unroll
    for (int reg = 0; reg < 4; reg++) {
      int b = b0 + 16 * w + lg * 4 + reg;
      int d = nf * 16 + lr;
      pc[((((size_t)si * B_TOT + b) * NHEAD + h) << 6) + d] = ctx[nf][reg];
    }
  if (lr == 0) {
#pragma unroll
    for (int reg = 0; reg < 4; reg++) {
      int b = b0 + 16 * w + lg * 4 + reg;
      size_t base = (((size_t)si * B_TOT + b) * NHEAD + h) * 2;
      pml[base] = m[reg];
      pml[base + 1] = l[reg];
    }
  }
}

// ---------------- combine split partials ----------------
__global__ void combine_k(const float* __restrict__ pc, const float* __restrict__ pml,
                          const float* __restrict__ vm, float* __restrict__ ctx) {
  const int b = blockIdx.x, t = threadIdx.x;
  const int h = t >> 6, d = t & 63;
  float ms[NSPLIT], ls[NSPLIT];
  float M = -3e38f;
#pragma unroll
  for (int si = 0; si < NSPLIT; si++) {
    size_t base = (((size_t)si * B_TOT + b) * NHEAD + h) * 2;
    ms[si] = pml[base];
    ls[si] = pml[base + 1];
    M = fmaxf(M, ms[si]);
  }
  float L = 0.f, a = 0.f;
#pragma unroll
  for (int si = 0; si < NSPLIT; si++) {
    float wgt = __expf(ms[si] - M);
    L += ls[si] * wgt;
    a += wgt * pc[((((size_t)si * B_TOT + b) * NHEAD + h) << 6) + d];
  }
  float r = (M < -1e8f) ? vm[t] : (a / L);
  ctx[(size_t)b * 256 + t] = r;
}

// ---------------- launch ----------------
extern "C" void kernel_launch(void* const* d_in, const int* in_sizes, int n_in,
                              void* d_out, int out_size, void* d_ws, size_t ws_size,
                              hipStream_t stream) {
  const int*   act = (const int*)d_in[0];
  const float* nc  = (const float*)d_in[1];
  const float* emb = (const float*)d_in[2];
  const float* ipw = (const float*)d_in[3];
  const float* ipb = (const float*)d_in[4];
  const float* opw = (const float*)d_in[5];
  const float* opb = (const float*)d_in[6];
  float* out = (float*)d_out;
  char* ws = (char*)d_ws;

  size_t off = 0;
  auto alloc = [&](size_t bytes) { size_t r0 = off; off = (off + bytes + 255) & ~(size_t)255; return r0; };
  u16*   wqkv = (u16*)(ws + alloc(768 * 256 * 2));
  u16*   wout = (u16*)(ws + alloc(256 * 256 * 2));
  u16*   qb   = (u16*)(ws + alloc((size_t)B_TOT * 256 * 2));
  u16*   kbuf = (u16*)(ws + alloc((size_t)S_TOT * 256 * 2));
  u16*   vtb  = (u16*)(ws + alloc((size_t)256 * S_LD * 2));
  float* cmp  = (float*)(ws + alloc(80 * 256 * 4));
  float* vm   = (float*)(ws + alloc(256 * 4));
  float* pc   = (float*)(ws + alloc((size_t)NSPLIT * B_TOT * NHEAD * 64 * 4));
  float* pml  = (float*)(ws + alloc((size_t)NSPLIT * B_TOT * NHEAD * 2 * 4));
  float* ctxf = (float*)(ws + alloc((size_t)B_TOT * 256 * 4));

  convert_w<<<1024, 256, 0, stream>>>(ipw, opw, wqkv, wout);
  zero_vt_pad<<<32, 256, 0, stream>>>(vtb);
  colmean_part<<<80, 256, 0, stream>>>(emb, cmp);
  vmean_k<<<1, 256, 0, stream>>>(cmp, ipw, ipb, vm);
  // q projection: rows 0..255 of in_proj
  gemm_bt<0><<<dim3(16, 4), 256, 0, stream>>>(nc, wqkv, ipb, B_TOT, qb, nullptr, nullptr, nullptr);
  // kv projection: rows 256..767 of in_proj; N=512 (K cols 0..255, V cols 256..511)
  gemm_bt<1><<<dim3(313, 8), 256, 0, stream>>>(emb, wqkv + 256 * 256, ipb + 256, S_TOT,
                                               nullptr, kbuf, vtb, nullptr);
  attn_k<<<dim3(NSPLIT, 16, 4), 256, 0, stream>>>(qb, kbuf, vtb, act, pc, pml);
  combine_k<<<B_TOT, 256, 0, stream>>>(pc, pml, vm, ctxf);
  gemm_bt<2><<<dim3(16, 4), 256, 0, stream>>>(ctxf, wout, opb, B_TOT, nullptr, nullptr, nullptr, out);
}